// Round 14
// baseline (1286.705 us; speedup 1.0000x reference)
//
#include <hip/hip_runtime.h>

#define B_ 4
#define S_ 1024
#define D_ 1024
#define F_ 4096
#define H_ 16
#define L_ 6
#define M_ (B_*S_)

#define LOG2E 1.44269504088896f

typedef unsigned short u16;
typedef __attribute__((ext_vector_type(4))) unsigned short u16x4;
typedef __attribute__((ext_vector_type(8))) short s16x8;
typedef __attribute__((ext_vector_type(8))) __bf16 bf16x8;
typedef __attribute__((ext_vector_type(4))) float f32x4;

typedef const __attribute__((address_space(1))) unsigned int gu32;
typedef __attribute__((address_space(3))) unsigned int su32;

__device__ __forceinline__ u16 f2bf(float f) {
  union { float f; unsigned u; } v; v.f = f;
  unsigned u = v.u;
  return (u16)((u + 0x7fffu + ((u >> 16) & 1u)) >> 16);  // RNE
}
__device__ __forceinline__ float bf2f(u16 h) {
  union { unsigned u; float f; } v; v.u = (unsigned)h << 16; return v.f;
}

__device__ __forceinline__ f32x4 mfma16(s16x8 a, s16x8 b, f32x4 c) {
  return __builtin_amdgcn_mfma_f32_16x16x32_bf16(
      __builtin_bit_cast(bf16x8, a), __builtin_bit_cast(bf16x8, b), c, 0, 0, 0);
}

__device__ __forceinline__ void gload16(const void* g, void* s) {
  __builtin_amdgcn_global_load_lds((gu32*)g, (su32*)s, 16, 0, 0);
}

// T1: bijective XCD-chunked remap (nwg % 8 == 0) -> each XCD gets a
// contiguous chunk of tile ids, localizing B-panel reuse in its L2.
__device__ __forceinline__ int xcd_swz(int flat, int nwg) {
  return (flat >> 3) + (flat & 7) * (nwg >> 3);
}

// ============ 128x128 m97-structure GEMM (2-barrier, linear LDS) ============
// OUTMODE 1: bf16 raw (split-K partial)
// OUTMODE 3: fused-QKV; z block-uniform (bn>>10); z==2 writes V in Vt layout
template<int OUTMODE>
__device__ __forceinline__ void gemm128_body(
    const u16* __restrict__ A, const u16* __restrict__ Bt,
    const float* __restrict__ b0, const float* __restrict__ b1,
    const float* __restrict__ b2, u16* __restrict__ Ch,
    u16* __restrict__ Vt, int N, int K, int kbeg, int kend, int bm, int bn)
{
  __shared__ __align__(16) u16 As[128 * 64];
  __shared__ __align__(16) u16 Bs[128 * 64];
  const int tid = threadIdx.x, lane = tid & 63, w = tid >> 6;
  const int wm = (w >> 1) * 64, wn = (w & 1) * 64;

  f32x4 acc[4][4];
#pragma unroll
  for (int i = 0; i < 4; i++)
#pragma unroll
    for (int j = 0; j < 4; j++) acc[i][j] = {0.f, 0.f, 0.f, 0.f};

  for (int k0 = kbeg; k0 < kend; k0 += 64) {
    __syncthreads();
#pragma unroll
    for (int i = 0; i < 4; i++) {
      const int flat = i * 4096 + w * 1024 + lane * 16;  // bytes in tile
      const int row = flat >> 7, ce = (flat & 127) >> 1;
      gload16(A + (size_t)(bm + row) * K + k0 + ce, As + i * 2048 + w * 512);
      gload16(Bt + (size_t)(bn + row) * K + k0 + ce, Bs + i * 2048 + w * 512);
    }
    __syncthreads();
#pragma unroll
    for (int kk = 0; kk < 2; kk++) {
      s16x8 af[4], bf[4];
#pragma unroll
      for (int mf = 0; mf < 4; mf++)
        af[mf] = *(const s16x8*)&As[(wm + mf * 16 + (lane & 15)) * 64 + kk * 32 + (lane >> 4) * 8];
#pragma unroll
      for (int nf = 0; nf < 4; nf++)
        bf[nf] = *(const s16x8*)&Bs[(wn + nf * 16 + (lane & 15)) * 64 + kk * 32 + (lane >> 4) * 8];
#pragma unroll
      for (int mf = 0; mf < 4; mf++)
#pragma unroll
        for (int nf = 0; nf < 4; nf++)
          acc[mf][nf] = mfma16(af[mf], bf[nf], acc[mf][nf]);
    }
  }

  if (OUTMODE == 3) {
    const int zz = bn >> 10;                 // block-uniform (128 | 1024)
    const int lcb = (bn & 1023) + wn;
    const float* bp = (zz == 0) ? b0 : (zz == 1) ? b1 : b2;
    if (zz == 2) {
      // V: write directly transposed -> Vt[(b*16+h)*64+dh][s]
      const int b = bm >> 10;                // block-uniform (128 | 1024)
#pragma unroll
      for (int nf = 0; nf < 4; nf++) {
        const int dh2 = lcb + nf * 16 + (lane & 15);
        const int hq = dh2 >> 6, dh = dh2 & 63;
        const float bv = bp[dh2];
        u16* vrow = Vt + ((size_t)((b << 4) + hq) * 64 + dh) * S_;
#pragma unroll
        for (int mf = 0; mf < 4; mf++) {
          const int s0 = (bm & 1023) + wm + mf * 16 + ((lane >> 4) << 2);
          u16x4 hv;
#pragma unroll
          for (int j = 0; j < 4; j++) hv[j] = f2bf(acc[mf][nf][j] + bv);
          *(u16x4*)(vrow + s0) = hv;
        }
      }
    } else {
      const float sc = (zz == 0) ? (0.125f * LOG2E) : 1.0f;  // Q scaled for exp2
      u16* Outz = Ch + (size_t)zz * M_ * D_;
#pragma unroll
      for (int nf = 0; nf < 4; nf++) {
        const int col = lcb + nf * 16 + (lane & 15);
        const float bv = bp[col];
#pragma unroll
        for (int mf = 0; mf < 4; mf++) {
#pragma unroll
          for (int j = 0; j < 4; j++) {
            const int row = bm + wm + mf * 16 + ((lane >> 4) << 2) + j;
            Outz[(size_t)row * D_ + col] = f2bf((acc[mf][nf][j] + bv) * sc);
          }
        }
      }
    }
  } else {
#pragma unroll
    for (int nf = 0; nf < 4; nf++) {
      const int col = bn + wn + nf * 16 + (lane & 15);
#pragma unroll
      for (int mf = 0; mf < 4; mf++) {
#pragma unroll
        for (int j = 0; j < 4; j++) {
          const int row = bm + wm + mf * 16 + ((lane >> 4) << 2) + j;
          Ch[(size_t)row * N + col] = f2bf(acc[mf][nf][j]);
        }
      }
    }
  }
}

// fused QKV: 768 blocks, XCD-swizzled; Q|K row-major (Q pre-scaled), V -> Vt
__global__ __launch_bounds__(256, 3) void gemm_qkvf(
    const u16* __restrict__ A, const u16* __restrict__ WT,
    const float* __restrict__ bq, const float* __restrict__ bk,
    const float* __restrict__ bv, u16* __restrict__ Out, u16* __restrict__ Vt)
{
  const int idx = xcd_swz(blockIdx.y * 32 + blockIdx.x, 768);
  const int bm = (idx & 31) * 128, bn = (idx >> 5) * 128;
  gemm128_body<3>(A, WT, bq, bk, bv, Out, Vt, 3 * D_, D_, 0, D_, bm, bn);
}

// O-proj split-K2: 512 blocks, XCD-swizzled; bf16 partials (bias in LN)
__global__ __launch_bounds__(256, 3) void gemm_osplit2(
    const u16* __restrict__ A, const u16* __restrict__ WT,
    u16* __restrict__ P)
{
  const int idx = xcd_swz((blockIdx.z * 8 + blockIdx.y) * 32 + blockIdx.x, 512);
  const int bm = (idx & 31) * 128;
  const int rem = idx >> 5;              // 0..15
  const int bn = (rem & 7) * 128, z = rem >> 3;
  gemm128_body<1>(A, WT, nullptr, nullptr, nullptr,
                  P + (size_t)z * M_ * D_, nullptr, D_, D_,
                  z * 512, z * 512 + 512, bm, bn);
}

// ============ 256x256 8-phase GEMM (FFN; grid >= 256 blocks) ================
__device__ __forceinline__ s16x8 readfrag(const u16* half, int r, int kk, int hi4) {
  const int c = (kk * 64 + hi4 * 16) ^ ((r & 7) << 4);
  return *(const s16x8*)((const char*)half + r * 128 + c);
}

__device__ __forceinline__ void stage_half(
    const u16* __restrict__ src, int ldk, u16* lds_half, int w, int lane)
{
#pragma unroll
  for (int j = 0; j < 2; j++) {
    const int flat = j * 8192 + w * 1024 + lane * 16;   // byte in 16KB half
    const int row = flat >> 7;
    const int kb = (flat & 127) ^ ((row & 7) << 4);
    gload16(src + (size_t)row * ldk + (kb >> 1), lds_half + j * 4096 + w * 512);
  }
}

#define BAR     asm volatile("s_barrier" ::: "memory")
#define PH_PRE  asm volatile("s_barrier" ::: "memory"); __builtin_amdgcn_s_setprio(1)
#define PH_POST __builtin_amdgcn_s_setprio(0); __builtin_amdgcn_sched_barrier(0)
#define VM0     asm volatile("s_waitcnt vmcnt(0)" ::: "memory")
#define VM4     asm volatile("s_waitcnt vmcnt(4)" ::: "memory")

#define READ_B(bufhalf) do { \
  _Pragma("unroll") for (int nf = 0; nf < 4; nf++) \
  _Pragma("unroll") for (int kk = 0; kk < 2; kk++) \
    bfr[nf][kk] = readfrag(bufhalf, rb0 + nf * 16 + lo16, kk, hi4); } while (0)
#define READ_A(bufhalf, Q) do { \
  _Pragma("unroll") for (int m = 0; m < 2; m++) \
  _Pragma("unroll") for (int kk = 0; kk < 2; kk++) \
    af[m][kk] = readfrag(bufhalf, (2 * (Q) + m) * 16 + lo16, kk, hi4); } while (0)
#define DO_MFMA(Q) do { \
  _Pragma("unroll") for (int kk = 0; kk < 2; kk++) \
  _Pragma("unroll") for (int m = 0; m < 2; m++) \
  _Pragma("unroll") for (int nf = 0; nf < 4; nf++) \
    acc[2 * (Q) + m][nf] = mfma16(af[m][kk], bfr[nf][kk], acc[2 * (Q) + m][nf]); } while (0)

// OUTMODE 2: relu(acc+b0) bf16     4: bf16 raw (split-K partial)
template<int OUTMODE>
__device__ __forceinline__ void gemm256_body(
    const u16* __restrict__ A, const u16* __restrict__ Bt,
    const float* __restrict__ bias, u16* __restrict__ Ch,
    int N, int K, int kbeg, int kslice, int bm, int bn)
{
  __shared__ __align__(16) u16 As[2][2][8192];   // [parity][half][128x64]
  __shared__ __align__(16) u16 Bs[2][2][8192];
  const int tid = threadIdx.x, lane = tid & 63, w = tid >> 6;
  const int wr = w >> 2, wc = w & 3;
  const int lo16 = lane & 15, hi4 = lane >> 4;
  const int rb0 = (wc & 1) * 64;

  const u16* Abase = A + (size_t)bm * K + kbeg;
  const u16* Bbase = Bt + (size_t)bn * K + kbeg;
  const size_t h1 = (size_t)128 * K;
  const int NT = kslice >> 6, NI = NT >> 1;

  f32x4 acc[8][4];
#pragma unroll
  for (int i = 0; i < 8; i++)
#pragma unroll
    for (int j = 0; j < 4; j++) acc[i][j] = {0.f, 0.f, 0.f, 0.f};

  stage_half(Abase,           K, As[0][0], w, lane);
  stage_half(Abase + h1,      K, As[0][1], w, lane);
  stage_half(Bbase,           K, Bs[0][0], w, lane);
  stage_half(Bbase + h1,      K, Bs[0][1], w, lane);
  stage_half(Abase + 64,      K, As[1][0], w, lane);
  stage_half(Abase + h1 + 64, K, As[1][1], w, lane);
  stage_half(Bbase + 64,      K, Bs[1][0], w, lane);
  stage_half(Bbase + h1 + 64, K, Bs[1][1], w, lane);
  asm volatile("s_waitcnt vmcnt(8)" ::: "memory");
  BAR;

  const u16* Ae = As[0][wr]; const u16* Ao = As[1][wr];
  const u16* Be = Bs[0][wc >> 1]; const u16* Bo = Bs[1][wc >> 1];
  s16x8 af[2][2], bfr[4][2];

  for (int it = 0; it < NI - 1; ++it) {
    READ_B(Be); READ_A(Ae, 0);
    if (it > 0) {
      stage_half(Abase +      (size_t)(2 * it + 1) * 64, K, As[1][0], w, lane);
      stage_half(Abase + h1 + (size_t)(2 * it + 1) * 64, K, As[1][1], w, lane);
    }
    PH_PRE; DO_MFMA(0); PH_POST; BAR;
    READ_A(Ae, 1);
    stage_half(Bbase +      (size_t)(2 * it + 2) * 64, K, Bs[0][0], w, lane);
    PH_PRE; DO_MFMA(1); PH_POST; BAR;
    READ_A(Ae, 2);
    stage_half(Bbase + h1 + (size_t)(2 * it + 2) * 64, K, Bs[0][1], w, lane);
    PH_PRE; DO_MFMA(2); PH_POST; BAR;
    READ_A(Ae, 3);
    PH_PRE; DO_MFMA(3); PH_POST; VM4; BAR;
    READ_B(Bo); READ_A(Ao, 0);
    stage_half(Abase +      (size_t)(2 * it + 2) * 64, K, As[0][0], w, lane);
    stage_half(Abase + h1 + (size_t)(2 * it + 2) * 64, K, As[0][1], w, lane);
    PH_PRE; DO_MFMA(0); PH_POST; BAR;
    READ_A(Ao, 1);
    stage_half(Bbase +      (size_t)(2 * it + 3) * 64, K, Bs[1][0], w, lane);
    PH_PRE; DO_MFMA(1); PH_POST; BAR;
    READ_A(Ao, 2);
    stage_half(Bbase + h1 + (size_t)(2 * it + 3) * 64, K, Bs[1][1], w, lane);
    PH_PRE; DO_MFMA(2); PH_POST; BAR;
    READ_A(Ao, 3);
    PH_PRE; DO_MFMA(3); PH_POST; VM4; BAR;
  }
  // peeled final iteration (A(NT-1) staged here — round-3 bugfix retained)
  READ_B(Be); READ_A(Ae, 0);
  stage_half(Abase +      (size_t)(NT - 1) * 64, K, As[1][0], w, lane);
  stage_half(Abase + h1 + (size_t)(NT - 1) * 64, K, As[1][1], w, lane);
  PH_PRE; DO_MFMA(0); PH_POST; BAR;
  READ_A(Ae, 1);             PH_PRE; DO_MFMA(1); PH_POST; BAR;
  READ_A(Ae, 2);             PH_PRE; DO_MFMA(2); PH_POST; BAR;
  READ_A(Ae, 3);             PH_PRE; DO_MFMA(3); PH_POST; VM0; BAR;
  READ_B(Bo); READ_A(Ao, 0); PH_PRE; DO_MFMA(0); PH_POST; BAR;
  READ_A(Ao, 1);             PH_PRE; DO_MFMA(1); PH_POST; BAR;
  READ_A(Ao, 2);             PH_PRE; DO_MFMA(2); PH_POST; BAR;
  READ_A(Ao, 3);             PH_PRE; DO_MFMA(3); PH_POST;

  const int row0 = bm + wr * 128, col0 = bn + wc * 64;
#pragma unroll
  for (int nf = 0; nf < 4; nf++) {
    const int col = col0 + nf * 16 + lo16;
    const float bv = (OUTMODE == 2) ? bias[col] : 0.f;
#pragma unroll
    for (int mf = 0; mf < 8; mf++) {
#pragma unroll
      for (int j = 0; j < 4; j++) {
        const int row = row0 + mf * 16 + hi4 * 4 + j;
        float v = acc[mf][nf][j];
        if (OUTMODE == 2) v = fmaxf(v + bv, 0.f);
        Ch[(size_t)row * N + col] = f2bf(v);
      }
    }
  }
}

__global__ __launch_bounds__(512, 2) void gemm_ffn1(
    const u16* __restrict__ A, const u16* __restrict__ WT,
    const float* __restrict__ bias, u16* __restrict__ Out)
{
  const int idx = xcd_swz(blockIdx.y * 16 + blockIdx.x, 256);
  const int bm = (idx & 15) * 256, bn = (idx >> 4) * 256;
  gemm256_body<2>(A, WT, bias, Out, F_, D_, 0, D_, bm, bn);
}

__global__ __launch_bounds__(512, 2) void gemm_ffn2sp4(
    const u16* __restrict__ A, const u16* __restrict__ WT,
    u16* __restrict__ P)
{
  const int idx = xcd_swz((blockIdx.z * 4 + blockIdx.y) * 16 + blockIdx.x, 256);
  const int bm = (idx & 15) * 256;
  const int rem = idx >> 4;              // 0..15
  const int bn = (rem & 3) * 256, z = rem >> 2;
  gemm256_body<4>(A, WT, nullptr, P + (size_t)z * M_ * D_,
                  D_, F_, z * 1024, 1024, bm, bn);
}

// ---------------- per-layer weight transpose, 64x64 tiles ------------------
__global__ __launch_bounds__(256) void transpose_layer(
    const float* __restrict__ Wq, const float* __restrict__ Wk,
    const float* __restrict__ Wv, const float* __restrict__ Wo,
    const float* __restrict__ W1, const float* __restrict__ W2,
    u16* __restrict__ WT)
{
  __shared__ float tl[64][65];
  int bt = blockIdx.x;                 // 0..3071
  const float* src; u16* dst; int Rsrc, Csrc, cx, cy;
  if (bt < 1024) {
    const int m = bt >> 8; const int t = bt & 255;
    src = (m == 0) ? Wq : (m == 1) ? Wk : (m == 2) ? Wv : Wo;
    dst = WT + (size_t)m * 1024 * 1024;
    Rsrc = 1024; Csrc = 1024; cx = t & 15; cy = t >> 4;
  } else if (bt < 2048) {
    const int t = bt - 1024;
    src = W1; dst = WT + (size_t)4 * 1024 * 1024;
    Rsrc = 1024; Csrc = 4096; cx = t & 63; cy = t >> 6;
  } else {
    const int t = bt - 2048;
    src = W2; dst = WT + (size_t)8 * 1024 * 1024;
    Rsrc = 4096; Csrc = 1024; cx = t & 15; cy = t >> 4;
  }
  const int r0 = cy * 64, c0 = cx * 64;
  const int tid = threadIdx.x;
  const int rl = tid >> 2, q = tid & 3;
  const float* sp = src + (size_t)(r0 + rl) * Csrc + c0 + q * 16;
#pragma unroll
  for (int i = 0; i < 4; i++) {
    const float4 v = *(const float4*)(sp + i * 4);
    tl[rl][q * 16 + i * 4 + 0] = v.x;
    tl[rl][q * 16 + i * 4 + 1] = v.y;
    tl[rl][q * 16 + i * 4 + 2] = v.z;
    tl[rl][q * 16 + i * 4 + 3] = v.w;
  }
  __syncthreads();
#pragma unroll
  for (int it = 0; it < 2; it++) {
    const int idx = tid + it * 256;
    const int cl = idx >> 3, seg = idx & 7;
    const int rw0 = seg * 8;
    s16x8 v8;
#pragma unroll
    for (int u = 0; u < 8; u++) v8[u] = (short)f2bf(tl[rw0 + u][cl]);
    *(s16x8*)(dst + (size_t)(c0 + cl) * Rsrc + r0 + rw0) = v8;
  }
}

// ---------------- rel-bias LUT (x log2e) and mask->addend (x log2e) --------
__global__ __launch_bounds__(256) void build_lut(
    const float* __restrict__ rb, float* __restrict__ lut_g)
{
  const int h = blockIdx.x, l = blockIdx.y;
  for (int idx = threadIdx.x; idx < 2048; idx += 256) {
    const int rel = idx - 1024;
    const int ret = rel < 0 ? 16 : 0;
    const int n = rel < 0 ? -rel : rel;
    int bu;
    if (n < 8) bu = ret + n;
    else {
      const float t = logf((float)n * 0.125f) * (8.0f / 3.4657359027997265f);
      int vl = 8 + (int)t;
      if (vl > 15) vl = 15;
      bu = ret + vl;
    }
    lut_g[(size_t)(l * H_ + h) * 2048 + idx] = rb[l * 512 + bu * 16 + h] * (8.0f * LOG2E);
  }
}

__global__ __launch_bounds__(256) void mask2neg(
    const int* __restrict__ mask, u16* __restrict__ mf)
{
  const int i = blockIdx.x * 256 + threadIdx.x;
  if (i < B_ * S_) mf[i] = mask[i] ? (u16)0 : f2bf(-1e10f * LOG2E);
}

// ---------------- flash attention: 8-wave, max-free, exp2 ------------------
// (round-12 proven: triple-buffer counted-vmcnt, peel with vmcnt(0), setprio)
__device__ __forceinline__ s16x8 lds_swz(const u16* base, int row, int cb) {
  const int addr = row * 128 + (cb ^ ((row & 7) << 4));
  return *(const s16x8*)((const char*)base + addr);
}

#define ATTN_STAGE(t, buf) do { \
  const int kt2 = (t) * 64; \
  const int flat2 = tid * 16; \
  const int row2 = flat2 >> 7; \
  const int ce2 = ((flat2 & 127) ^ ((row2 & 7) << 4)) >> 1; \
  gload16(Kb + (size_t)(bS + kt2 + row2) * D_ + hh + ce2, Ks[buf] + w * 512); \
  gload16(Vt + (size_t)(bh * 64 + row2) * S_ + kt2 + ce2, Vs[buf] + w * 512); \
} while (0)

#define ATTN_TILE(bc, kt) do { \
    f32x4 sacc[4]; \
    _Pragma("unroll") for (int i = 0; i < 4; i++) sacc[i] = {0.f, 0.f, 0.f, 0.f}; \
    __builtin_amdgcn_s_setprio(1); \
    _Pragma("unroll") for (int kk = 0; kk < 2; kk++) { \
      const int cb = kk * 64 + hi4 * 16; \
      _Pragma("unroll") for (int nf = 0; nf < 4; nf++) { \
        const s16x8 kb = lds_swz(Ks[bc], nf * 16 + lo16, cb); \
        sacc[nf] = mfma16(qf[kk], kb, sacc[nf]); \
      } \
    } \
    __builtin_amdgcn_s_setprio(0); \
    float kmf[4]; \
    _Pragma("unroll") for (int nf = 0; nf < 4; nf++) \
      kmf[nf] = bf2f(maskf[(kt) + nf * 16 + lo16]); \
    const int lidx0 = q0 + hi4 * 4 + 1024 - (kt) - lo16; \
    _Pragma("unroll") for (int j = 0; j < 4; j++) { \
      const int lrow = (hi4 << 2) + j; \
      _Pragma("unroll") for (int nf = 0; nf < 4; nf++) { \
        const float s = sacc[nf][j] + kmf[nf] + lut[lidx0 + j - nf * 16]; \
        Ps[w][lrow * 68 + nf * 16 + lo16] = f2bf(__builtin_amdgcn_exp2f(s)); \
      } \
    } \
    __builtin_amdgcn_s_setprio(1); \
    _Pragma("unroll") for (int kk = 0; kk < 2; kk++) { \
      const s16x8 pa = *(const s16x8*)&Ps[w][lo16 * 68 + kk * 32 + hi4 * 8]; \
      const int cb = kk * 64 + hi4 * 16; \
      _Pragma("unroll") for (int df = 0; df < 4; df++) { \
        const s16x8 vb = lds_swz(Vs[bc], df * 16 + lo16, cb); \
        oacc[df] = mfma16(pa, vb, oacc[df]); \
      } \
      oacc[4] = mfma16(pa, onesf, oacc[4]); \
    } \
    __builtin_amdgcn_s_setprio(0); \
} while (0)

__global__ __launch_bounds__(512, 2) void attn_kernel(
    const u16* __restrict__ Qb, const u16* __restrict__ Kb,
    const u16* __restrict__ Vt, const u16* __restrict__ mask16,
    const float* __restrict__ lut_g, u16* __restrict__ AO)
{
  __shared__ __align__(16) float lut[2048];   // 8KB
  __shared__ __align__(16) u16 maskf[1024];   // 2KB
  __shared__ __align__(16) u16 Ks[3][64 * 64];
  __shared__ __align__(16) u16 Vs[3][64 * 64];
  __shared__ __align__(16) u16 Ps[8][16 * 68];

  const int tid = threadIdx.x;
  const int lane = tid & 63;
  const int w = tid >> 6;                 // 0..7
  const int bh = blockIdx.x;
  const int b = bh >> 4, h = bh & 15;
  const int q0 = blockIdx.y * 128 + w * 16;
  const int bS = b * S_, hh = h * 64;
  const int lo16 = lane & 15, hi4 = lane >> 4;

  const float* lsrc = lut_g + (size_t)h * 2048;
  gload16(lsrc + w * 256 + lane * 4, lut + w * 256);
  if (w < 2)
    gload16(mask16 + bS + w * 512 + lane * 8, maskf + w * 512);

  s16x8 qf[2];
#pragma unroll
  for (int kk = 0; kk < 2; kk++)
    qf[kk] = *(const s16x8*)(Qb + (size_t)(bS + q0 + lo16) * D_ + hh +
                             kk * 32 + hi4 * 8);

  s16x8 onesf;
#pragma unroll
  for (int u = 0; u < 8; u++) onesf[u] = (short)((lo16 == 0) ? 0x3F80 : 0);

  f32x4 oacc[5];   // [0..3]=O frags, [4]=row-sum l (col 0)
#pragma unroll
  for (int i = 0; i < 5; i++) oacc[i] = {0.f, 0.f, 0.f, 0.f};

  ATTN_STAGE(0, 0);
  ATTN_STAGE(1, 1);

  for (int t = 0; t < S_ / 64 - 1; ++t) {
    const int bc = t % 3;
    const int kt = t * 64;
    asm volatile("s_waitcnt vmcnt(2)" ::: "memory");  // tile t resident
    __builtin_amdgcn_s_barrier();                      // WAR: t-1 reads done
    if (t + 2 < S_ / 64) ATTN_STAGE(t + 2, (t + 2) % 3);
    ATTN_TILE(bc, kt);
  }
  {  // peeled last tile
    const int t = S_ / 64 - 1;
    asm volatile("s_waitcnt vmcnt(0)" ::: "memory");
    __builtin_amdgcn_s_barrier();
    ATTN_TILE(t % 3, t * 64);
  }

  float inv[4];
#pragma unroll
  for (int j = 0; j < 4; j++) {
    const float l = __shfl(oacc[4][j], lane & 48);
    inv[j] = 1.0f / l;
  }
#pragma unroll
  for (int df = 0; df < 4; df++)
#pragma unroll
    for (int j = 0; j < 4; j++) {
      const int qrow = q0 + (hi4 << 2) + j;
      AO[(size_t)(bS + qrow) * D_ + hh + df * 16 + lo16] =
          f2bf(oacc[df][j] * inv[j]);
    }
}

// ---------------- fused: Y = LN(Xh + sum(P bf16) + bias) -------------------
template<int NP>
__global__ __launch_bounds__(256) void ln_fusedb(
    const u16* __restrict__ Xh, const u16* __restrict__ P,
    const float* __restrict__ bias, const float* __restrict__ g,
    const float* __restrict__ be, u16* __restrict__ Yh, float* __restrict__ Yf)
{
  const int row = blockIdx.x;
  const int tid = threadIdx.x;
  const size_t off = (size_t)row * D_;
  const size_t ps = (size_t)M_ * D_;
  const u16x4 xv = ((const u16x4*)(Xh + off))[tid];
  float v[4];
#pragma unroll
  for (int q = 0; q < 4; q++) v[q] = bf2f(xv[q]);
#pragma unroll
  for (int p = 0; p < NP; p++) {
    const u16x4 pv = ((const u16x4*)(P + p * ps + off))[tid];
#pragma unroll
    for (int q = 0; q < 4; q++) v[q] += bf2f(pv[q]);
  }
  const float4 bb = ((const float4*)bias)[tid];
  v[0] += bb.x; v[1] += bb.y; v[2] += bb.z; v[3] += bb.w;

  float sum = v[0] + v[1] + v[2] + v[3];
  float ss = v[0] * v[0] + v[1] * v[1] + v[2] * v[2] + v[3] * v[3];
#pragma unroll
  for (int o = 1; o < 64; o <<= 1) {
    sum += __shfl_xor(sum, o);
    ss += __shfl_xor(ss, o);
  }
  __shared__ float s1[4], s2[4];
  if ((tid & 63) == 0) { s1[tid >> 6] = sum; s2[tid >> 6] = ss; }
  __syncthreads();
  sum = s1[0] + s1[1] + s1[2] + s1[3];
  ss = s2[0] + s2[1] + s2[2] + s2[3];
  const float mu = sum * (1.f / D_);
  const float var = ss * (1.f / D_) - mu * mu;
  const float rstd = rsqrtf(var + 1e-5f);
  const float4 gv = ((const float4*)g)[tid];
  const float4 bv = ((const float4*)be)[tid];
  float y[4];
  y[0] = (v[0] - mu) * rstd * gv.x + bv.x;
  y[1] = (v[1] - mu) * rstd * gv.y + bv.y;
  y[2] = (v[2] - mu) * rstd * gv.z + bv.z;
  y[3] = (v[3] - mu) * rstd * gv.w + bv.w;
  u16x4 hv;
  hv.x = f2bf(y[0]); hv.y = f2bf(y[1]); hv.z = f2bf(y[2]); hv.w = f2bf(y[3]);
  ((u16x4*)(Yh + off))[tid] = hv;
  if (Yf != nullptr) {
    float4 yf; yf.x = y[0]; yf.y = y[1]; yf.z = y[2]; yf.w = y[3];
    ((float4*)(Yf + off))[tid] = yf;
  }
}

// ---------------- embedding (bf16 out) -------------------------------------
__global__ __launch_bounds__(256) void embed_kernel(
    const int* __restrict__ src, const float* __restrict__ tok,
    const float* __restrict__ pos, u16* __restrict__ Xh)
{
  const int row = blockIdx.x;
  const int s = row & (S_ - 1);
  const int t = src[row];
  const int tid = threadIdx.x;
  const float4 tv = ((const float4*)(tok + (size_t)t * D_))[tid];
  const float4 pv = ((const float4*)(pos + (size_t)s * D_))[tid];
  u16x4 hv;
  hv.x = f2bf(tv.x * 32.f + pv.x);
  hv.y = f2bf(tv.y * 32.f + pv.y);
  hv.z = f2bf(tv.z * 32.f + pv.z);
  hv.w = f2bf(tv.w * 32.f + pv.w);
  ((u16x4*)(Xh + (size_t)row * D_))[tid] = hv;
}

// ---------------- launch ----------------------------------------------------
extern "C" void kernel_launch(void* const* d_in, const int* in_sizes, int n_in,
                              void* d_out, int out_size, void* d_ws, size_t ws_size,
                              hipStream_t stream)
{
  const int* src = (const int*)d_in[0];
  const int* mask = (const int*)d_in[1];
  const float* tok_emb = (const float*)d_in[2];
  const float* pos_emb = (const float*)d_in[3];
  const float* Wq = (const float*)d_in[4];
  const float* bq = (const float*)d_in[5];
  const float* Wk = (const float*)d_in[6];
  const float* bk = (const float*)d_in[7];
  const float* Wv = (const float*)d_in[8];
  const float* bv = (const float*)d_in[9];
  const float* Wo = (const float*)d_in[10];
  const float* bo = (const float*)d_in[11];
  const float* rb = (const float*)d_in[12];
  const float* g1 = (const float*)d_in[13];
  const float* b1n = (const float*)d_in[14];
  const float* W1 = (const float*)d_in[15];
  const float* b1f = (const float*)d_in[16];
  const float* W2 = (const float*)d_in[17];
  const float* b2f = (const float*)d_in[18];
  const float* g2 = (const float*)d_in[19];
  const float* b2n = (const float*)d_in[20];
  float* out = (float*)d_out;

  // ws map (~97 MB):
  //   0-8   xb16 | 8-16 Qb16 | 16-24 Kb16 | 24-32 Vt16 | 32-40 AO16
  //   8-40  Hb16 overlay (FFN; Q/K/Vt/AO dead there)
  //  40-72  Pp16 (4x8MB) | 72-96 WT (qkv 72, o 78, w1 80, w2 88)
  //  96+    lut_g (L*H*2048 f32) | +768KB mask16
  char* ws = (char*)d_ws;
  const size_t MB = 1ull << 20;
  u16* xb16  = (u16*)(ws + 0);
  u16* Qb16  = (u16*)(ws + 8 * MB);
  u16* Kb16  = (u16*)(ws + 16 * MB);
  u16* Vt16  = (u16*)(ws + 24 * MB);
  u16* AO16  = (u16*)(ws + 32 * MB);
  u16* Pp16  = (u16*)(ws + 40 * MB);
  u16* WT    = (u16*)(ws + 72 * MB);
  u16* Hb16  = (u16*)(ws + 8 * MB);
  float* lut_g  = (float*)(ws + 96 * MB);
  u16*   mask16 = (u16*)(ws + 96 * MB + 786432);

  u16* WTqkv = WT;
  u16* WTo   = WT + (size_t)3 * 1024 * 1024;
  u16* WT1   = WT + (size_t)4 * 1024 * 1024;
  u16* WT2   = WT + (size_t)8 * 1024 * 1024;

  embed_kernel<<<M_, 256, 0, stream>>>(src, tok_emb, pos_emb, xb16);
  build_lut<<<dim3(H_, L_), 256, 0, stream>>>(rb, lut_g);
  mask2neg<<<(B_ * S_ + 255) / 256, 256, 0, stream>>>(mask, mask16);

  for (int l = 0; l < L_; l++) {
    const size_t oDD = (size_t)l * D_ * D_;
    const size_t oDF = (size_t)l * D_ * F_;

    transpose_layer<<<3072, 256, 0, stream>>>(
        Wq + oDD, Wk + oDD, Wv + oDD, Wo + oDD, W1 + oDF, W2 + oDF, WT);

    gemm_qkvf<<<dim3(32, 24), 256, 0, stream>>>(
        xb16, WTqkv, bq + l * D_, bk + l * D_, bv + l * D_, Qb16, Vt16);

    attn_kernel<<<dim3(B_ * H_, S_ / 128), 512, 0, stream>>>(
        Qb16, Kb16, Vt16, mask16, lut_g + (size_t)l * H_ * 2048, AO16);

    gemm_osplit2<<<dim3(32, 8, 2), 256, 0, stream>>>(
        AO16, WTo, Pp16);

    ln_fusedb<2><<<M_, 256, 0, stream>>>(
        xb16, Pp16, bo + l * D_, g1 + l * D_, b1n + l * D_, xb16, nullptr);

    gemm_ffn1<<<dim3(16, 16), 512, 0, stream>>>(
        xb16, WT1, b1f + l * F_, Hb16);

    gemm_ffn2sp4<<<dim3(16, 4, 4), 512, 0, stream>>>(
        Hb16, WT2, Pp16);

    ln_fusedb<4><<<M_, 256, 0, stream>>>(
        xb16, Pp16, b2f + l * D_, g2 + l * D_, b2n + l * D_, xb16,
        (l == L_ - 1) ? out : nullptr);
  }
}

// Round 15
// 1232.237 us; speedup vs baseline: 1.0442x; 1.0442x over previous
//
#include <hip/hip_runtime.h>

#define B_ 4
#define S_ 1024
#define D_ 1024
#define F_ 4096
#define H_ 16
#define L_ 6
#define M_ (B_*S_)

#define LOG2E 1.44269504088896f

typedef unsigned short u16;
typedef __attribute__((ext_vector_type(4))) unsigned short u16x4;
typedef __attribute__((ext_vector_type(8))) short s16x8;
typedef __attribute__((ext_vector_type(8))) __bf16 bf16x8;
typedef __attribute__((ext_vector_type(4))) float f32x4;

typedef const __attribute__((address_space(1))) unsigned int gu32;
typedef __attribute__((address_space(3))) unsigned int su32;

__device__ __forceinline__ u16 f2bf(float f) {
  union { float f; unsigned u; } v; v.f = f;
  unsigned u = v.u;
  return (u16)((u + 0x7fffu + ((u >> 16) & 1u)) >> 16);  // RNE
}
__device__ __forceinline__ float bf2f(u16 h) {
  union { unsigned u; float f; } v; v.u = (unsigned)h << 16; return v.f;
}

__device__ __forceinline__ f32x4 mfma16(s16x8 a, s16x8 b, f32x4 c) {
  return __builtin_amdgcn_mfma_f32_16x16x32_bf16(
      __builtin_bit_cast(bf16x8, a), __builtin_bit_cast(bf16x8, b), c, 0, 0, 0);
}

__device__ __forceinline__ void gload16(const void* g, void* s) {
  __builtin_amdgcn_global_load_lds((gu32*)g, (su32*)s, 16, 0, 0);
}

// ============ 128x128 m97-structure GEMM (2-barrier, linear LDS) ============
// OUTMODE 1: bf16 raw (split-K partial)
// OUTMODE 3: fused-QKV; z block-uniform (bn>>10); z==2 writes V in Vt layout
template<int OUTMODE>
__device__ __forceinline__ void gemm128_body(
    const u16* __restrict__ A, const u16* __restrict__ Bt,
    const float* __restrict__ b0, const float* __restrict__ b1,
    const float* __restrict__ b2, u16* __restrict__ Ch,
    u16* __restrict__ Vt, int N, int K, int kbeg, int kend)
{
  __shared__ __align__(16) u16 As[128 * 64];
  __shared__ __align__(16) u16 Bs[128 * 64];
  const int tid = threadIdx.x, lane = tid & 63, w = tid >> 6;
  const int bm = blockIdx.x * 128, bn = blockIdx.y * 128;
  const int wm = (w >> 1) * 64, wn = (w & 1) * 64;

  f32x4 acc[4][4];
#pragma unroll
  for (int i = 0; i < 4; i++)
#pragma unroll
    for (int j = 0; j < 4; j++) acc[i][j] = {0.f, 0.f, 0.f, 0.f};

  for (int k0 = kbeg; k0 < kend; k0 += 64) {
    __syncthreads();
#pragma unroll
    for (int i = 0; i < 4; i++) {
      const int flat = i * 4096 + w * 1024 + lane * 16;  // bytes in tile
      const int row = flat >> 7, ce = (flat & 127) >> 1;
      gload16(A + (size_t)(bm + row) * K + k0 + ce, As + i * 2048 + w * 512);
      gload16(Bt + (size_t)(bn + row) * K + k0 + ce, Bs + i * 2048 + w * 512);
    }
    __syncthreads();
#pragma unroll
    for (int kk = 0; kk < 2; kk++) {
      s16x8 af[4], bf[4];
#pragma unroll
      for (int mf = 0; mf < 4; mf++)
        af[mf] = *(const s16x8*)&As[(wm + mf * 16 + (lane & 15)) * 64 + kk * 32 + (lane >> 4) * 8];
#pragma unroll
      for (int nf = 0; nf < 4; nf++)
        bf[nf] = *(const s16x8*)&Bs[(wn + nf * 16 + (lane & 15)) * 64 + kk * 32 + (lane >> 4) * 8];
#pragma unroll
      for (int mf = 0; mf < 4; mf++)
#pragma unroll
        for (int nf = 0; nf < 4; nf++)
          acc[mf][nf] = mfma16(af[mf], bf[nf], acc[mf][nf]);
    }
  }

  if (OUTMODE == 3) {
    const int zz = bn >> 10;                 // block-uniform (128 | 1024)
    const int lcb = (bn & 1023) + wn;
    const float* bp = (zz == 0) ? b0 : (zz == 1) ? b1 : b2;
    if (zz == 2) {
      // V: write directly transposed -> Vt[(b*16+h)*64+dh][s]
      const int b = bm >> 10;                // block-uniform (128 | 1024)
#pragma unroll
      for (int nf = 0; nf < 4; nf++) {
        const int dh2 = lcb + nf * 16 + (lane & 15);
        const int hq = dh2 >> 6, dh = dh2 & 63;
        const float bv = bp[dh2];
        u16* vrow = Vt + ((size_t)((b << 4) + hq) * 64 + dh) * S_;
#pragma unroll
        for (int mf = 0; mf < 4; mf++) {
          const int s0 = (bm & 1023) + wm + mf * 16 + ((lane >> 4) << 2);
          u16x4 hv;
#pragma unroll
          for (int j = 0; j < 4; j++) hv[j] = f2bf(acc[mf][nf][j] + bv);
          *(u16x4*)(vrow + s0) = hv;
        }
      }
    } else {
      const float sc = (zz == 0) ? (0.125f * LOG2E) : 1.0f;  // Q scaled for exp2
      u16* Outz = Ch + (size_t)zz * M_ * D_;
#pragma unroll
      for (int nf = 0; nf < 4; nf++) {
        const int col = lcb + nf * 16 + (lane & 15);
        const float bv = bp[col];
#pragma unroll
        for (int mf = 0; mf < 4; mf++) {
#pragma unroll
          for (int j = 0; j < 4; j++) {
            const int row = bm + wm + mf * 16 + ((lane >> 4) << 2) + j;
            Outz[(size_t)row * D_ + col] = f2bf((acc[mf][nf][j] + bv) * sc);
          }
        }
      }
    }
  } else {
#pragma unroll
    for (int nf = 0; nf < 4; nf++) {
      const int col = bn + wn + nf * 16 + (lane & 15);
#pragma unroll
      for (int mf = 0; mf < 4; mf++) {
#pragma unroll
        for (int j = 0; j < 4; j++) {
          const int row = bm + wm + mf * 16 + ((lane >> 4) << 2) + j;
          Ch[(size_t)row * N + col] = f2bf(acc[mf][nf][j]);
        }
      }
    }
  }
}

// fused QKV: Bt = [WTq;WTk;WTv]; Q|K row-major (Q pre-scaled), V -> Vt layout
__global__ __launch_bounds__(256, 3) void gemm_qkvf(
    const u16* __restrict__ A, const u16* __restrict__ WT,
    const float* __restrict__ bq, const float* __restrict__ bk,
    const float* __restrict__ bv, u16* __restrict__ Out, u16* __restrict__ Vt)
{
  gemm128_body<3>(A, WT, bq, bk, bv, Out, Vt, 3 * D_, D_, 0, D_);
}

// O-proj split-K2, bf16 partials (bias added in LN)
__global__ __launch_bounds__(256, 3) void gemm_osplit2(
    const u16* __restrict__ A, const u16* __restrict__ WT,
    u16* __restrict__ P)
{
  const int z = blockIdx.z;
  gemm128_body<1>(A, WT, nullptr, nullptr, nullptr,
                  P + (size_t)z * M_ * D_, nullptr, D_, D_, z * 512, z * 512 + 512);
}

// ============ 256x256 8-phase GEMM (grid >= 256 blocks only) ================
__device__ __forceinline__ s16x8 readfrag(const u16* half, int r, int kk, int hi4) {
  const int c = (kk * 64 + hi4 * 16) ^ ((r & 7) << 4);
  return *(const s16x8*)((const char*)half + r * 128 + c);
}

__device__ __forceinline__ void stage_half(
    const u16* __restrict__ src, int ldk, u16* lds_half, int w, int lane)
{
#pragma unroll
  for (int j = 0; j < 2; j++) {
    const int flat = j * 8192 + w * 1024 + lane * 16;   // byte in 16KB half
    const int row = flat >> 7;
    const int kb = (flat & 127) ^ ((row & 7) << 4);
    gload16(src + (size_t)row * ldk + (kb >> 1), lds_half + j * 4096 + w * 512);
  }
}

#define BAR     asm volatile("s_barrier" ::: "memory")
#define PH_PRE  asm volatile("s_barrier" ::: "memory"); __builtin_amdgcn_s_setprio(1)
#define PH_POST __builtin_amdgcn_s_setprio(0); __builtin_amdgcn_sched_barrier(0)
#define VM4     asm volatile("s_waitcnt vmcnt(4)" ::: "memory")
#define VM0     asm volatile("s_waitcnt vmcnt(0)" ::: "memory")

#define READ_B(bufhalf) do { \
  _Pragma("unroll") for (int nf = 0; nf < 4; nf++) \
  _Pragma("unroll") for (int kk = 0; kk < 2; kk++) \
    bfr[nf][kk] = readfrag(bufhalf, rb0 + nf * 16 + lo16, kk, hi4); } while (0)
#define READ_A(bufhalf, Q) do { \
  _Pragma("unroll") for (int m = 0; m < 2; m++) \
  _Pragma("unroll") for (int kk = 0; kk < 2; kk++) \
    af[m][kk] = readfrag(bufhalf, (2 * (Q) + m) * 16 + lo16, kk, hi4); } while (0)
#define DO_MFMA(Q) do { \
  _Pragma("unroll") for (int kk = 0; kk < 2; kk++) \
  _Pragma("unroll") for (int m = 0; m < 2; m++) \
  _Pragma("unroll") for (int nf = 0; nf < 4; nf++) \
    acc[2 * (Q) + m][nf] = mfma16(af[m][kk], bfr[nf][kk], acc[2 * (Q) + m][nf]); } while (0)

// OUTMODE 2: relu(acc+b0) bf16     4: bf16 raw (split-K partial)
template<int OUTMODE>
__device__ __forceinline__ void gemm256_body(
    const u16* __restrict__ A, const u16* __restrict__ Bt,
    const float* __restrict__ bias, u16* __restrict__ Ch,
    int N, int K, int kbeg, int kslice)
{
  __shared__ __align__(16) u16 As[2][2][8192];   // [parity][half][128x64]
  __shared__ __align__(16) u16 Bs[2][2][8192];
  const int tid = threadIdx.x, lane = tid & 63, w = tid >> 6;
  const int wr = w >> 2, wc = w & 3;
  const int lo16 = lane & 15, hi4 = lane >> 4;
  const int bm = blockIdx.x * 256, bn = blockIdx.y * 256;
  const int rb0 = (wc & 1) * 64;

  const u16* Abase = A + (size_t)bm * K + kbeg;
  const u16* Bbase = Bt + (size_t)bn * K + kbeg;
  const size_t h1 = (size_t)128 * K;
  const int NT = kslice >> 6, NI = NT >> 1;

  f32x4 acc[8][4];
#pragma unroll
  for (int i = 0; i < 8; i++)
#pragma unroll
    for (int j = 0; j < 4; j++) acc[i][j] = {0.f, 0.f, 0.f, 0.f};

  stage_half(Abase,           K, As[0][0], w, lane);
  stage_half(Abase + h1,      K, As[0][1], w, lane);
  stage_half(Bbase,           K, Bs[0][0], w, lane);
  stage_half(Bbase + h1,      K, Bs[0][1], w, lane);
  stage_half(Abase + 64,      K, As[1][0], w, lane);
  stage_half(Abase + h1 + 64, K, As[1][1], w, lane);
  stage_half(Bbase + 64,      K, Bs[1][0], w, lane);
  stage_half(Bbase + h1 + 64, K, Bs[1][1], w, lane);
  asm volatile("s_waitcnt vmcnt(8)" ::: "memory");
  BAR;

  const u16* Ae = As[0][wr]; const u16* Ao = As[1][wr];
  const u16* Be = Bs[0][wc >> 1]; const u16* Bo = Bs[1][wc >> 1];
  s16x8 af[2][2], bfr[4][2];

  for (int it = 0; it < NI - 1; ++it) {
    READ_B(Be); READ_A(Ae, 0);
    if (it > 0) {
      stage_half(Abase +      (size_t)(2 * it + 1) * 64, K, As[1][0], w, lane);
      stage_half(Abase + h1 + (size_t)(2 * it + 1) * 64, K, As[1][1], w, lane);
    }
    PH_PRE; DO_MFMA(0); PH_POST; BAR;
    READ_A(Ae, 1);
    stage_half(Bbase +      (size_t)(2 * it + 2) * 64, K, Bs[0][0], w, lane);
    PH_PRE; DO_MFMA(1); PH_POST; BAR;
    READ_A(Ae, 2);
    stage_half(Bbase + h1 + (size_t)(2 * it + 2) * 64, K, Bs[0][1], w, lane);
    PH_PRE; DO_MFMA(2); PH_POST; BAR;
    READ_A(Ae, 3);
    PH_PRE; DO_MFMA(3); PH_POST; VM4; BAR;
    READ_B(Bo); READ_A(Ao, 0);
    stage_half(Abase +      (size_t)(2 * it + 2) * 64, K, As[0][0], w, lane);
    stage_half(Abase + h1 + (size_t)(2 * it + 2) * 64, K, As[0][1], w, lane);
    PH_PRE; DO_MFMA(0); PH_POST; BAR;
    READ_A(Ao, 1);
    stage_half(Bbase +      (size_t)(2 * it + 3) * 64, K, Bs[1][0], w, lane);
    PH_PRE; DO_MFMA(1); PH_POST; BAR;
    READ_A(Ao, 2);
    stage_half(Bbase + h1 + (size_t)(2 * it + 3) * 64, K, Bs[1][1], w, lane);
    PH_PRE; DO_MFMA(2); PH_POST; BAR;
    READ_A(Ao, 3);
    PH_PRE; DO_MFMA(3); PH_POST; VM4; BAR;
  }
  // peeled final iteration (A(NT-1) staged here — round-3 bugfix retained)
  READ_B(Be); READ_A(Ae, 0);
  stage_half(Abase +      (size_t)(NT - 1) * 64, K, As[1][0], w, lane);
  stage_half(Abase + h1 + (size_t)(NT - 1) * 64, K, As[1][1], w, lane);
  PH_PRE; DO_MFMA(0); PH_POST; BAR;
  READ_A(Ae, 1);             PH_PRE; DO_MFMA(1); PH_POST; BAR;
  READ_A(Ae, 2);             PH_PRE; DO_MFMA(2); PH_POST; BAR;
  READ_A(Ae, 3);             PH_PRE; DO_MFMA(3); PH_POST; VM0; BAR;
  READ_B(Bo); READ_A(Ao, 0); PH_PRE; DO_MFMA(0); PH_POST; BAR;
  READ_A(Ao, 1);             PH_PRE; DO_MFMA(1); PH_POST; BAR;
  READ_A(Ao, 2);             PH_PRE; DO_MFMA(2); PH_POST; BAR;
  READ_A(Ao, 3);             PH_PRE; DO_MFMA(3); PH_POST;

  const int row0 = bm + wr * 128, col0 = bn + wc * 64;
#pragma unroll
  for (int nf = 0; nf < 4; nf++) {
    const int col = col0 + nf * 16 + lo16;
    const float bv = (OUTMODE == 2) ? bias[col] : 0.f;
#pragma unroll
    for (int mf = 0; mf < 8; mf++) {
#pragma unroll
      for (int j = 0; j < 4; j++) {
        const int row = row0 + mf * 16 + hi4 * 4 + j;
        float v = acc[mf][nf][j];
        if (OUTMODE == 2) v = fmaxf(v + bv, 0.f);
        Ch[(size_t)row * N + col] = f2bf(v);
      }
    }
  }
}

__global__ __launch_bounds__(512, 2) void gemm_ffn1(
    const u16* __restrict__ A, const u16* __restrict__ WT,
    const float* __restrict__ bias, u16* __restrict__ Out)
{
  gemm256_body<2>(A, WT, bias, Out, F_, D_, 0, D_);
}

__global__ __launch_bounds__(512, 2) void gemm_ffn2sp4(
    const u16* __restrict__ A, const u16* __restrict__ WT,
    u16* __restrict__ P)
{
  const int z = blockIdx.z;
  gemm256_body<4>(A, WT, nullptr, P + (size_t)z * M_ * D_,
                  D_, F_, z * 1024, 1024);
}

// ---------------- per-layer weight transpose, 64x64 tiles ------------------
__global__ __launch_bounds__(256) void transpose_layer(
    const float* __restrict__ Wq, const float* __restrict__ Wk,
    const float* __restrict__ Wv, const float* __restrict__ Wo,
    const float* __restrict__ W1, const float* __restrict__ W2,
    u16* __restrict__ WT)
{
  __shared__ float tl[64][65];
  int bt = blockIdx.x;                 // 0..3071
  const float* src; u16* dst; int Rsrc, Csrc, cx, cy;
  if (bt < 1024) {
    const int m = bt >> 8; const int t = bt & 255;
    src = (m == 0) ? Wq : (m == 1) ? Wk : (m == 2) ? Wv : Wo;
    dst = WT + (size_t)m * 1024 * 1024;
    Rsrc = 1024; Csrc = 1024; cx = t & 15; cy = t >> 4;
  } else if (bt < 2048) {
    const int t = bt - 1024;
    src = W1; dst = WT + (size_t)4 * 1024 * 1024;
    Rsrc = 1024; Csrc = 4096; cx = t & 63; cy = t >> 6;
  } else {
    const int t = bt - 2048;
    src = W2; dst = WT + (size_t)8 * 1024 * 1024;
    Rsrc = 4096; Csrc = 1024; cx = t & 15; cy = t >> 4;
  }
  const int r0 = cy * 64, c0 = cx * 64;
  const int tid = threadIdx.x;
  const int rl = tid >> 2, q = tid & 3;
  const float* sp = src + (size_t)(r0 + rl) * Csrc + c0 + q * 16;
#pragma unroll
  for (int i = 0; i < 4; i++) {
    const float4 v = *(const float4*)(sp + i * 4);
    tl[rl][q * 16 + i * 4 + 0] = v.x;
    tl[rl][q * 16 + i * 4 + 1] = v.y;
    tl[rl][q * 16 + i * 4 + 2] = v.z;
    tl[rl][q * 16 + i * 4 + 3] = v.w;
  }
  __syncthreads();
#pragma unroll
  for (int it = 0; it < 2; it++) {
    const int idx = tid + it * 256;
    const int cl = idx >> 3, seg = idx & 7;
    const int rw0 = seg * 8;
    s16x8 v8;
#pragma unroll
    for (int u = 0; u < 8; u++) v8[u] = (short)f2bf(tl[rw0 + u][cl]);
    *(s16x8*)(dst + (size_t)(c0 + cl) * Rsrc + r0 + rw0) = v8;
  }
}

// ---------------- rel-bias LUT (x log2e) and mask->addend (x log2e) --------
__global__ __launch_bounds__(256) void build_lut(
    const float* __restrict__ rb, float* __restrict__ lut_g)
{
  const int h = blockIdx.x, l = blockIdx.y;
  for (int idx = threadIdx.x; idx < 2048; idx += 256) {
    const int rel = idx - 1024;
    const int ret = rel < 0 ? 16 : 0;
    const int n = rel < 0 ? -rel : rel;
    int bu;
    if (n < 8) bu = ret + n;
    else {
      const float t = logf((float)n * 0.125f) * (8.0f / 3.4657359027997265f);
      int vl = 8 + (int)t;
      if (vl > 15) vl = 15;
      bu = ret + vl;
    }
    lut_g[(size_t)(l * H_ + h) * 2048 + idx] = rb[l * 512 + bu * 16 + h] * (8.0f * LOG2E);
  }
}

__global__ __launch_bounds__(256) void mask2neg(
    const int* __restrict__ mask, u16* __restrict__ mf)
{
  const int i = blockIdx.x * 256 + threadIdx.x;
  if (i < B_ * S_) mf[i] = mask[i] ? (u16)0 : f2bf(-1e10f * LOG2E);
}

// ---------------- flash attention: 8-wave, max-free, exp2 ------------------
// Triple-buffered counted-vmcnt pipeline (2-tile prefetch depth); peel with
// vmcnt(0); setprio(1) around MFMA clusters.
__device__ __forceinline__ s16x8 lds_swz(const u16* base, int row, int cb) {
  const int addr = row * 128 + (cb ^ ((row & 7) << 4));
  return *(const s16x8*)((const char*)base + addr);
}

#define ATTN_STAGE(t, buf) do { \
  const int kt2 = (t) * 64; \
  const int flat2 = tid * 16; \
  const int row2 = flat2 >> 7; \
  const int ce2 = ((flat2 & 127) ^ ((row2 & 7) << 4)) >> 1; \
  gload16(Kb + (size_t)(bS + kt2 + row2) * D_ + hh + ce2, Ks[buf] + w * 512); \
  gload16(Vt + (size_t)(bh * 64 + row2) * S_ + kt2 + ce2, Vs[buf] + w * 512); \
} while (0)

#define ATTN_TILE(bc, kt) do { \
    f32x4 sacc[4]; \
    _Pragma("unroll") for (int i = 0; i < 4; i++) sacc[i] = {0.f, 0.f, 0.f, 0.f}; \
    __builtin_amdgcn_s_setprio(1); \
    _Pragma("unroll") for (int kk = 0; kk < 2; kk++) { \
      const int cb = kk * 64 + hi4 * 16; \
      _Pragma("unroll") for (int nf = 0; nf < 4; nf++) { \
        const s16x8 kb = lds_swz(Ks[bc], nf * 16 + lo16, cb); \
        sacc[nf] = mfma16(qf[kk], kb, sacc[nf]); \
      } \
    } \
    __builtin_amdgcn_s_setprio(0); \
    float kmf[4]; \
    _Pragma("unroll") for (int nf = 0; nf < 4; nf++) \
      kmf[nf] = bf2f(maskf[(kt) + nf * 16 + lo16]); \
    const int lidx0 = q0 + hi4 * 4 + 1024 - (kt) - lo16; \
    _Pragma("unroll") for (int j = 0; j < 4; j++) { \
      const int lrow = (hi4 << 2) + j; \
      _Pragma("unroll") for (int nf = 0; nf < 4; nf++) { \
        const float s = sacc[nf][j] + kmf[nf] + lut[lidx0 + j - nf * 16]; \
        Ps[w][lrow * 68 + nf * 16 + lo16] = f2bf(__builtin_amdgcn_exp2f(s)); \
      } \
    } \
    __builtin_amdgcn_s_setprio(1); \
    _Pragma("unroll") for (int kk = 0; kk < 2; kk++) { \
      const s16x8 pa = *(const s16x8*)&Ps[w][lo16 * 68 + kk * 32 + hi4 * 8]; \
      const int cb = kk * 64 + hi4 * 16; \
      _Pragma("unroll") for (int df = 0; df < 4; df++) { \
        const s16x8 vb = lds_swz(Vs[bc], df * 16 + lo16, cb); \
        oacc[df] = mfma16(pa, vb, oacc[df]); \
      } \
      oacc[4] = mfma16(pa, onesf, oacc[4]); \
    } \
    __builtin_amdgcn_s_setprio(0); \
} while (0)

__global__ __launch_bounds__(512, 2) void attn_kernel(
    const u16* __restrict__ Qb, const u16* __restrict__ Kb,
    const u16* __restrict__ Vt, const u16* __restrict__ mask16,
    const float* __restrict__ lut_g, u16* __restrict__ AO)
{
  __shared__ __align__(16) float lut[2048];   // 8KB
  __shared__ __align__(16) u16 maskf[1024];   // 2KB
  __shared__ __align__(16) u16 Ks[3][64 * 64];
  __shared__ __align__(16) u16 Vs[3][64 * 64];
  __shared__ __align__(16) u16 Ps[8][16 * 68];

  const int tid = threadIdx.x;
  const int lane = tid & 63;
  const int w = tid >> 6;                 // 0..7
  const int bh = blockIdx.x;
  const int b = bh >> 4, h = bh & 15;
  const int q0 = blockIdx.y * 128 + w * 16;
  const int bS = b * S_, hh = h * 64;
  const int lo16 = lane & 15, hi4 = lane >> 4;

  const float* lsrc = lut_g + (size_t)h * 2048;
  gload16(lsrc + w * 256 + lane * 4, lut + w * 256);
  if (w < 2)
    gload16(mask16 + bS + w * 512 + lane * 8, maskf + w * 512);

  s16x8 qf[2];
#pragma unroll
  for (int kk = 0; kk < 2; kk++)
    qf[kk] = *(const s16x8*)(Qb + (size_t)(bS + q0 + lo16) * D_ + hh +
                             kk * 32 + hi4 * 8);

  s16x8 onesf;
#pragma unroll
  for (int u = 0; u < 8; u++) onesf[u] = (short)((lo16 == 0) ? 0x3F80 : 0);

  f32x4 oacc[5];   // [0..3]=O frags, [4]=row-sum l (col 0)
#pragma unroll
  for (int i = 0; i < 5; i++) oacc[i] = {0.f, 0.f, 0.f, 0.f};

  ATTN_STAGE(0, 0);
  ATTN_STAGE(1, 1);

  for (int t = 0; t < S_ / 64 - 1; ++t) {
    const int bc = t % 3;
    const int kt = t * 64;
    asm volatile("s_waitcnt vmcnt(2)" ::: "memory");  // tile t resident
    __builtin_amdgcn_s_barrier();                      // WAR: t-1 reads done
    if (t + 2 < S_ / 64) ATTN_STAGE(t + 2, (t + 2) % 3);
    ATTN_TILE(bc, kt);
  }
  {  // peeled last tile: only stage(NT-1) outstanding -> need full drain
    const int t = S_ / 64 - 1;
    asm volatile("s_waitcnt vmcnt(0)" ::: "memory");
    __builtin_amdgcn_s_barrier();
    ATTN_TILE(t % 3, t * 64);
  }

  float inv[4];
#pragma unroll
  for (int j = 0; j < 4; j++) {
    const float l = __shfl(oacc[4][j], lane & 48);  // broadcast col0 of group
    inv[j] = 1.0f / l;
  }
#pragma unroll
  for (int df = 0; df < 4; df++)
#pragma unroll
    for (int j = 0; j < 4; j++) {
      const int qrow = q0 + (hi4 << 2) + j;
      AO[(size_t)(bS + qrow) * D_ + hh + df * 16 + lo16] =
          f2bf(oacc[df][j] * inv[j]);
    }
}

// ---------------- fused: Y = LN(Xh + sum(P bf16) + bias) -------------------
template<int NP>
__global__ __launch_bounds__(256) void ln_fusedb(
    const u16* __restrict__ Xh, const u16* __restrict__ P,
    const float* __restrict__ bias, const float* __restrict__ g,
    const float* __restrict__ be, u16* __restrict__ Yh, float* __restrict__ Yf)
{
  const int row = blockIdx.x;
  const int tid = threadIdx.x;
  const size_t off = (size_t)row * D_;
  const size_t ps = (size_t)M_ * D_;
  const u16x4 xv = ((const u16x4*)(Xh + off))[tid];
  float v[4];
#pragma unroll
  for (int q = 0; q < 4; q++) v[q] = bf2f(xv[q]);
#pragma unroll
  for (int p = 0; p < NP; p++) {
    const u16x4 pv = ((const u16x4*)(P + p * ps + off))[tid];
#pragma unroll
    for (int q = 0; q < 4; q++) v[q] += bf2f(pv[q]);
  }
  const float4 bb = ((const float4*)bias)[tid];
  v[0] += bb.x; v[1] += bb.y; v[2] += bb.z; v[3] += bb.w;

  float sum = v[0] + v[1] + v[2] + v[3];
  float ss = v[0] * v[0] + v[1] * v[1] + v[2] * v[2] + v[3] * v[3];
#pragma unroll
  for (int o = 1; o < 64; o <<= 1) {
    sum += __shfl_xor(sum, o);
    ss += __shfl_xor(ss, o);
  }
  __shared__ float s1[4], s2[4];
  if ((tid & 63) == 0) { s1[tid >> 6] = sum; s2[tid >> 6] = ss; }
  __syncthreads();
  sum = s1[0] + s1[1] + s1[2] + s1[3];
  ss = s2[0] + s2[1] + s2[2] + s2[3];
  const float mu = sum * (1.f / D_);
  const float var = ss * (1.f / D_) - mu * mu;
  const float rstd = rsqrtf(var + 1e-5f);
  const float4 gv = ((const float4*)g)[tid];
  const float4 bv = ((const float4*)be)[tid];
  float y[4];
  y[0] = (v[0] - mu) * rstd * gv.x + bv.x;
  y[1] = (v[1] - mu) * rstd * gv.y + bv.y;
  y[2] = (v[2] - mu) * rstd * gv.z + bv.z;
  y[3] = (v[3] - mu) * rstd * gv.w + bv.w;
  u16x4 hv;
  hv.x = f2bf(y[0]); hv.y = f2bf(y[1]); hv.z = f2bf(y[2]); hv.w = f2bf(y[3]);
  ((u16x4*)(Yh + off))[tid] = hv;
  if (Yf != nullptr) {
    float4 yf; yf.x = y[0]; yf.y = y[1]; yf.z = y[2]; yf.w = y[3];
    ((float4*)(Yf + off))[tid] = yf;
  }
}

// ---------------- embedding (bf16 out) -------------------------------------
__global__ __launch_bounds__(256) void embed_kernel(
    const int* __restrict__ src, const float* __restrict__ tok,
    const float* __restrict__ pos, u16* __restrict__ Xh)
{
  const int row = blockIdx.x;
  const int s = row & (S_ - 1);
  const int t = src[row];
  const int tid = threadIdx.x;
  const float4 tv = ((const float4*)(tok + (size_t)t * D_))[tid];
  const float4 pv = ((const float4*)(pos + (size_t)s * D_))[tid];
  u16x4 hv;
  hv.x = f2bf(tv.x * 32.f + pv.x);
  hv.y = f2bf(tv.y * 32.f + pv.y);
  hv.z = f2bf(tv.z * 32.f + pv.z);
  hv.w = f2bf(tv.w * 32.f + pv.w);
  ((u16x4*)(Xh + (size_t)row * D_))[tid] = hv;
}

// ---------------- launch ----------------------------------------------------
extern "C" void kernel_launch(void* const* d_in, const int* in_sizes, int n_in,
                              void* d_out, int out_size, void* d_ws, size_t ws_size,
                              hipStream_t stream)
{
  const int* src = (const int*)d_in[0];
  const int* mask = (const int*)d_in[1];
  const float* tok_emb = (const float*)d_in[2];
  const float* pos_emb = (const float*)d_in[3];
  const float* Wq = (const float*)d_in[4];
  const float* bq = (const float*)d_in[5];
  const float* Wk = (const float*)d_in[6];
  const float* bk = (const float*)d_in[7];
  const float* Wv = (const float*)d_in[8];
  const float* bv = (const float*)d_in[9];
  const float* Wo = (const float*)d_in[10];
  const float* bo = (const float*)d_in[11];
  const float* rb = (const float*)d_in[12];
  const float* g1 = (const float*)d_in[13];
  const float* b1n = (const float*)d_in[14];
  const float* W1 = (const float*)d_in[15];
  const float* b1f = (const float*)d_in[16];
  const float* W2 = (const float*)d_in[17];
  const float* b2f = (const float*)d_in[18];
  const float* g2 = (const float*)d_in[19];
  const float* b2n = (const float*)d_in[20];
  float* out = (float*)d_out;

  // ws map (~97 MB):
  //   0-8   xb16 | 8-16 Qb16 | 16-24 Kb16 | 24-32 Vt16 | 32-40 AO16
  //   8-40  Hb16 overlay (FFN; Q/K/Vt/AO dead there)
  //  40-72  Pp16 (4x8MB) | 72-96 WT (qkv 72, o 78, w1 80, w2 88)
  //  96+    lut_g (L*H*2048 f32) | +768KB mask16
  char* ws = (char*)d_ws;
  const size_t MB = 1ull << 20;
  u16* xb16  = (u16*)(ws + 0);
  u16* Qb16  = (u16*)(ws + 8 * MB);
  u16* Kb16  = (u16*)(ws + 16 * MB);
  u16* Vt16  = (u16*)(ws + 24 * MB);
  u16* AO16  = (u16*)(ws + 32 * MB);
  u16* Pp16  = (u16*)(ws + 40 * MB);
  u16* WT    = (u16*)(ws + 72 * MB);
  u16* Hb16  = (u16*)(ws + 8 * MB);
  float* lut_g  = (float*)(ws + 96 * MB);
  u16*   mask16 = (u16*)(ws + 96 * MB + 786432);

  u16* WTqkv = WT;
  u16* WTo   = WT + (size_t)3 * 1024 * 1024;
  u16* WT1   = WT + (size_t)4 * 1024 * 1024;
  u16* WT2   = WT + (size_t)8 * 1024 * 1024;

  embed_kernel<<<M_, 256, 0, stream>>>(src, tok_emb, pos_emb, xb16);
  build_lut<<<dim3(H_, L_), 256, 0, stream>>>(rb, lut_g);
  mask2neg<<<(B_ * S_ + 255) / 256, 256, 0, stream>>>(mask, mask16);

  for (int l = 0; l < L_; l++) {
    const size_t oDD = (size_t)l * D_ * D_;
    const size_t oDF = (size_t)l * D_ * F_;

    transpose_layer<<<3072, 256, 0, stream>>>(
        Wq + oDD, Wk + oDD, Wv + oDD, Wo + oDD, W1 + oDF, W2 + oDF, WT);

    gemm_qkvf<<<dim3(M_ / 128, 3 * D_ / 128), 256, 0, stream>>>(
        xb16, WTqkv, bq + l * D_, bk + l * D_, bv + l * D_, Qb16, Vt16);

    attn_kernel<<<dim3(B_ * H_, S_ / 128), 512, 0, stream>>>(
        Qb16, Kb16, Vt16, mask16, lut_g + (size_t)l * H_ * 2048, AO16);

    gemm_osplit2<<<dim3(M_ / 128, D_ / 128, 2), 256, 0, stream>>>(
        AO16, WTo, Pp16);

    ln_fusedb<2><<<M_, 256, 0, stream>>>(
        xb16, Pp16, bo + l * D_, g1 + l * D_, b1n + l * D_, xb16, nullptr);

    gemm_ffn1<<<dim3(M_ / 256, F_ / 256), 512, 0, stream>>>(
        xb16, WT1, b1f + l * F_, Hb16);

    gemm_ffn2sp4<<<dim3(M_ / 256, D_ / 256, 4), 512, 0, stream>>>(
        Hb16, WT2, Pp16);

    ln_fusedb<4><<<M_, 256, 0, stream>>>(
        xb16, Pp16, b2f + l * D_, g2 + l * D_, b2n + l * D_, xb16,
        (l == L_ - 1) ? out : nullptr);
  }
}